// Round 5
// baseline (202.673 us; speedup 1.0000x reference)
//
#include <hip/hip_runtime.h>
#include <math.h>

typedef _Float16 f16;
typedef __attribute__((ext_vector_type(8))) _Float16 f16x8;
typedef __attribute__((ext_vector_type(4))) _Float16 f16x4;
typedef __attribute__((ext_vector_type(4))) float f32x4;

#define NSEQ 4096
#define DIN 1024
#define DOUT 1024

// async global->LDS, 16B per lane; LDS dest must be wave-uniform base + lane*16
__device__ __forceinline__ void load16(const void* g, void* l) {
    __builtin_amdgcn_global_load_lds(
        (const __attribute__((address_space(1))) unsigned int*)g,
        (__attribute__((address_space(3))) unsigned int*)l, 16, 0, 0);
}

#define MEMFENCE asm volatile("" ::: "memory")
#define BAR() do { MEMFENCE; __builtin_amdgcn_s_barrier(); MEMFENCE; } while (0)

#define MM(I, J, KH, AR) \
    acc[I][J] = __builtin_amdgcn_mfma_f32_16x16x32_f16(AR[KH], b##J[KH], acc[I][J], 0, 0, 0)

// one phase's MFMA cluster: 2 m-frags x 4 n x 2 khalves = 16 MFMA, prio-wrapped (T5)
#define MFMA16(I0, I1) \
    __builtin_amdgcn_s_setprio(1); \
    MM(I0,0,0,a0); MM(I0,1,0,a0); MM(I0,2,0,a0); MM(I0,3,0,a0); \
    MM(I1,0,0,a1); MM(I1,1,0,a1); MM(I1,2,0,a1); MM(I1,3,0,a1); \
    MM(I0,0,1,a0); MM(I0,1,1,a0); MM(I0,2,1,a0); MM(I0,3,1,a0); \
    MM(I1,0,1,a1); MM(I1,1,1,a1); MM(I1,2,1,a1); MM(I1,3,1,a1); \
    __builtin_amdgcn_s_setprio(0)

// ---------------- 256x256 8-phase kernel (S and PV) ----------------
// C[M,N] = scale*(A[M,K] @ B[N,K]^T).  BK=64, 8 waves (2Mx4N), 128 KiB LDS
// double-buffered, 4 phases/K-tile x {ds_read subtile || 2 global_load_lds ->
// BAR -> setprio MFMA16 -> BAR}, counted vmcnt(4) once per tile (T3+T4+T5).
// R5 FIX vs R4: buffer stride is 32768 BYTES (As = 2*2*256*32 f16 = 65536 B
// total / 2 bufs), R4 wrongly used 65536 -> buf1(A) aliased buf0(B) and
// buf1(B) ran past the LDS block => absmax 0.16.  All three uses fixed.
// Layout per array: [buf(32768B)][kh(16384B)][row(64B)][32 f16].
// Staging is coalesced (16x 64B segments per load16): row-major LDS rows with
// intra-row chunk swizzle c(r)=(r+(r>>2))&3 (c invariant under r+16/r+128),
// global src permuted only within each row's 64B segment.
// B(t+2) restages into buf[cur].B: safe -- every wave's B-consuming MFMA is
// between P1's two barriers, >=2 barriers before any wave's P3 stB issue.
// vmcnt(4) at tile end: 8 oldest (= A(t+1),B(t+1)) land, B(t+2) stays in flight.
template <typename OutT, int EPI>
__global__ __launch_bounds__(512, 2)
void gemm8(const f16* __restrict__ A, const f16* __restrict__ B,
           OutT* __restrict__ c0, OutT* __restrict__ c1,
           OutT* __restrict__ c2, OutT* __restrict__ c3,
           int M, int N, int K, int lda, int ldb, int ldc, float scale,
           long aStrideZ, long bStrideZ, float* __restrict__ Sums)
{
    const int z = blockIdx.z;
    A += (long)z * aStrideZ;
    B += (long)z * bStrideZ;
    OutT* C = z == 0 ? c0 : (z == 1 ? c1 : (z == 2 ? c2 : c3));
    __shared__ f16 As[2 * 2 * 256 * 32];   // 64 KB: [buf][kh][row][32]
    __shared__ f16 Bs[2 * 2 * 256 * 32];   // 64 KB

    // ---- XCD swizzle: 8x4 patches when gx>=8; chunked (=> 4x2 patches at
    // gx=4) otherwise. Both bijective for our grids. ----
    const int gx = gridDim.x;
    const int bid = blockIdx.y * gx + blockIdx.x;
    int bx, by;
    if (gx >= 8) {
        int xcd = bid & 7, s = bid >> 3;
        int px = s & 7, rest = s >> 3;
        int py = rest & 3, chunk = rest >> 2;
        int pg = xcd + (chunk << 3);
        int pcols = gx >> 3;
        int lp = 31 - __clz(pcols);
        bx = ((pg & (pcols - 1)) << 3) + px;
        by = ((pg >> lp) << 2) + py;
    } else {
        int nwg = gx * gridDim.y;
        int nb = (bid & 7) * (nwg >> 3) + (bid >> 3);
        bx = nb % gx; by = nb / gx;
    }

    const int t    = threadIdx.x;
    const int lane = t & 63;
    const int w    = t >> 6;            // 0..7
    const int wm   = (w >> 2) * 128;    // 0,128
    const int wn   = (w & 3) * 64;      // 0..192
    const int tile_m = by * 256;
    const int tile_n = bx * 256;
    const int quad = lane >> 4;
    const int l16  = lane & 15;
    // staging: thread t -> row t>>2 (and +128 via rb), slot t&3; slot j holds
    // logical chunk (j + c(row))&3, c(r) = (r + (r>>2))&3
    const int srow = t >> 2;
    const int scol = (((t & 3) + srow + (srow >> 2)) & 3) * 8;
    // read: logical chunk q=quad lives at physical slot (q - c(l16))&3
    const int qx16 = ((quad - (l16 + (l16 >> 2))) & 3) * 16;

    f32x4 acc[8][4];
#pragma unroll
    for (int i = 0; i < 8; i++)
#pragma unroll
        for (int j = 0; j < 4; j++) acc[i][j] = (f32x4){0.f, 0.f, 0.f, 0.f};

    const f16* Ag = A + (long)(tile_m + srow) * lda + scol;
    const f16* Bg = B + (long)(tile_n + srow) * ldb + scol;
    const long a128 = (long)128 * lda, b128 = (long)128 * ldb;
    char* AsW = (char*)As + t * 16;     // byte dest base (wave-uniform + lane*16)
    char* BsW = (char*)Bs + t * 16;
    const char* aRd = (const char*)As + (wm + l16) * 64 + qx16;
    const char* bRd = (const char*)Bs + (wn + l16) * 64 + qx16;

    auto stA = [&](int buf, int kh, int rb, int k0) {
        load16(Ag + k0 + kh * 32 + (long)rb * a128,
               AsW + buf * 32768 + kh * 16384 + rb * 8192);
    };
    auto stB = [&](int buf, int kh, int rb, int k0) {
        load16(Bg + k0 + kh * 32 + (long)rb * b128,
               BsW + buf * 32768 + kh * 16384 + rb * 8192);
    };

    const int nt = K >> 6;
    // prologue: A(0),B(0)->buf0; B(1)->buf1 stays partially in flight
    stA(0,0,0,0); stA(0,0,1,0); stA(0,1,0,0); stA(0,1,1,0);
    stB(0,0,0,0); stB(0,0,1,0); stB(0,1,0,0); stB(0,1,1,0);
    if (nt > 1) {
        stB(1,0,0,64); stB(1,0,1,64); stB(1,1,0,64); stB(1,1,1,64);
        asm volatile("s_waitcnt vmcnt(4)" ::: "memory");
    } else {
        asm volatile("s_waitcnt vmcnt(0)" ::: "memory");
    }
    BAR();

    for (int ti = 0; ti < nt; ++ti) {
        const int cur = ti & 1;
        const char* aR = aRd + cur * 32768;
        const char* bR = bRd + cur * 32768;
        const int k1 = (ti + 1) << 6;
        const int k2 = (ti + 2) << 6;
        f16x8 b0[2], b1[2], b2[2], b3[2], a0[2], a1[2];
        // ---- P1: all B + A m0,m1; stage A(t+1) kh0 ----
        b0[0] = *(const f16x8*)(bR);          b0[1] = *(const f16x8*)(bR + 16384);
        b1[0] = *(const f16x8*)(bR + 1024);   b1[1] = *(const f16x8*)(bR + 17408);
        b2[0] = *(const f16x8*)(bR + 2048);   b2[1] = *(const f16x8*)(bR + 18432);
        b3[0] = *(const f16x8*)(bR + 3072);   b3[1] = *(const f16x8*)(bR + 19456);
        a0[0] = *(const f16x8*)(aR);          a0[1] = *(const f16x8*)(aR + 16384);
        a1[0] = *(const f16x8*)(aR + 1024);   a1[1] = *(const f16x8*)(aR + 17408);
        if (ti + 1 < nt) { stA(cur ^ 1, 0, 0, k1); stA(cur ^ 1, 0, 1, k1); }
        BAR();
        __builtin_amdgcn_sched_barrier(0);
        MFMA16(0, 1);
        BAR();
        // ---- P2: A m2,m3; stage A(t+1) kh1 ----
        a0[0] = *(const f16x8*)(aR + 2048);   a0[1] = *(const f16x8*)(aR + 18432);
        a1[0] = *(const f16x8*)(aR + 3072);   a1[1] = *(const f16x8*)(aR + 19456);
        if (ti + 1 < nt) { stA(cur ^ 1, 1, 0, k1); stA(cur ^ 1, 1, 1, k1); }
        BAR();
        __builtin_amdgcn_sched_barrier(0);
        MFMA16(2, 3);
        BAR();
        // ---- P3: A m4,m5; stage B(t+2) kh0 into buf[cur] (B consumed in P1) ----
        a0[0] = *(const f16x8*)(aR + 4096);   a0[1] = *(const f16x8*)(aR + 20480);
        a1[0] = *(const f16x8*)(aR + 5120);   a1[1] = *(const f16x8*)(aR + 21504);
        if (ti + 2 < nt) { stB(cur, 0, 0, k2); stB(cur, 0, 1, k2); }
        BAR();
        __builtin_amdgcn_sched_barrier(0);
        MFMA16(4, 5);
        BAR();
        // ---- P4: A m6,m7; stage B(t+2) kh1; counted drain ----
        a0[0] = *(const f16x8*)(aR + 6144);   a0[1] = *(const f16x8*)(aR + 22528);
        a1[0] = *(const f16x8*)(aR + 7168);   a1[1] = *(const f16x8*)(aR + 23552);
        if (ti + 2 < nt) { stB(cur, 1, 0, k2); stB(cur, 1, 1, k2); }
        BAR();
        __builtin_amdgcn_sched_barrier(0);
        MFMA16(6, 7);
        if (ti + 2 < nt)      asm volatile("s_waitcnt vmcnt(4)" ::: "memory");
        else if (ti + 1 < nt) asm volatile("s_waitcnt vmcnt(0)" ::: "memory");
        BAR();
    }

    // epilogue: D row = quad*4 + reg, col = lane&15 (verified m89/m91 layout)
    if (EPI == 2) {
        const int bxs = bx * 4 + (wn >> 6);   // 16 bx * 4 wave-cols = 64 chunks
#pragma unroll
        for (int i = 0; i < 8; i++) {
            float rs[4] = {0.f, 0.f, 0.f, 0.f};
#pragma unroll
            for (int j = 0; j < 4; j++)
#pragma unroll
                for (int r = 0; r < 4; r++) {
                    float e = __expf(acc[i][j][r] * scale);
                    int row = tile_m + wm + i * 16 + quad * 4 + r;
                    int col = tile_n + wn + j * 16 + l16;
                    C[(long)row * ldc + col] = (OutT)e;
                    rs[r] += e;
                }
#pragma unroll
            for (int msk = 1; msk < 16; msk <<= 1)
#pragma unroll
                for (int r = 0; r < 4; r++)
                    rs[r] += __shfl_xor(rs[r], msk, 64);
            if (l16 == 0)
#pragma unroll
                for (int r = 0; r < 4; r++) {
                    int row = tile_m + wm + i * 16 + quad * 4 + r;
                    Sums[(long)row * 64 + bxs] = rs[r];
                }
        }
    } else {
#pragma unroll
        for (int i = 0; i < 8; i++)
#pragma unroll
            for (int j = 0; j < 4; j++)
#pragma unroll
                for (int r = 0; r < 4; r++) {
                    int row = tile_m + wm + i * 16 + quad * 4 + r;
                    int col = tile_n + wn + j * 16 + l16;
                    C[(long)row * ldc + col] = (OutT)(acc[i][j][r] * scale);
                }
    }
}

// ---------------- 128x128 proven kernel (QKV) ----------------
template <typename OutT, int EPI>
__global__ __launch_bounds__(256, 2)
void gemm_bt(const f16* __restrict__ A, const f16* __restrict__ B,
             OutT* __restrict__ c0, OutT* __restrict__ c1,
             OutT* __restrict__ c2, OutT* __restrict__ c3,
             int M, int N, int K, int lda, int ldb, int ldc, float scale,
             long aStrideZ, long bStrideZ,
             f16* __restrict__ TC, int tz, int ldt, float* __restrict__ Sums)
{
    const int z = blockIdx.z;
    A += (long)z * aStrideZ;
    B += (long)z * bStrideZ;
    OutT* C = z == 0 ? c0 : (z == 1 ? c1 : (z == 2 ? c2 : c3));
    __shared__ f16 As[2 * 128 * 32];
    __shared__ f16 Bs[2 * 128 * 32];

    int gx = gridDim.x;
    int bid = blockIdx.y * gx + blockIdx.x;
    int xcd = bid & 7, s = bid >> 3;
    int px = s & 7, rest = s >> 3;
    int py = rest & 3, chunk = rest >> 2;
    int pg = xcd + (chunk << 3);
    int pcols = gx >> 3;
    int lp = 31 - __clz(pcols);
    int bx = ((pg & (pcols - 1)) << 3) + px;
    int by = ((pg >> lp) << 2) + py;

    const int t    = threadIdx.x;
    const int lane = t & 63;
    const int wave = t >> 6;
    const int wm   = (wave >> 1) * 64;
    const int wn   = (wave & 1) * 64;
    const int tile_m = by * 128;
    const int tile_n = bx * 128;
    const int quad = lane >> 4;
    const int l16  = lane & 15;
    const int srow = t >> 2;
    const int scol = (((t & 3) + srow + (srow >> 2)) & 3) * 8;
    const int qx8 = ((quad - (l16 + (l16 >> 2))) & 3) * 8;

    f32x4 acc[4][4];
#pragma unroll
    for (int i = 0; i < 4; i++)
#pragma unroll
        for (int j = 0; j < 4; j++)
            acc[i][j] = (f32x4){0.f, 0.f, 0.f, 0.f};

    const f16* Ab = A + (long)(tile_m + srow) * lda + scol;
    const f16* Bb = B + (long)(tile_n + srow) * ldb + scol;
    f16* Asd = As + t * 8;
    f16* Bsd = Bs + t * 8;

    for (int k0 = 0; k0 < K; k0 += 64) {
        load16(Ab + k0, Asd);
        load16(Ab + (long)64 * lda + k0, Asd + 2048);
        load16(Ab + k0 + 32, Asd + 4096);
        load16(Ab + (long)64 * lda + k0 + 32, Asd + 4096 + 2048);
        load16(Bb + k0, Bsd);
        load16(Bb + (long)64 * ldb + k0, Bsd + 2048);
        load16(Bb + k0 + 32, Bsd + 4096);
        load16(Bb + (long)64 * ldb + k0 + 32, Bsd + 4096 + 2048);
        __syncthreads();
#pragma unroll
        for (int p = 0; p < 2; p++) {
            f16x8 a[4], b[4];
#pragma unroll
            for (int i = 0; i < 4; i++)
                a[i] = *(const f16x8*)(As + p * 4096 + (wm + i * 16 + l16) * 32 + qx8);
#pragma unroll
            for (int j = 0; j < 4; j++)
                b[j] = *(const f16x8*)(Bs + p * 4096 + (wn + j * 16 + l16) * 32 + qx8);
#pragma unroll
            for (int i = 0; i < 4; i++)
#pragma unroll
                for (int j = 0; j < 4; j++)
                    acc[i][j] = __builtin_amdgcn_mfma_f32_16x16x32_f16(
                        a[i], b[j], acc[i][j], 0, 0, 0);
        }
        __syncthreads();
    }
    if (EPI == 1) {
        if (z == tz) {
#pragma unroll
            for (int i = 0; i < 4; i++)
#pragma unroll
                for (int j = 0; j < 4; j++) {
                    f16x4 o;
#pragma unroll
                    for (int r = 0; r < 4; r++) o[r] = (f16)(acc[i][j][r] * scale);
                    int row0 = tile_m + wm + i * 16 + quad * 4;
                    int col  = tile_n + wn + j * 16 + l16;
                    *(f16x4*)(TC + (long)col * ldt + row0) = o;
                }
        } else {
#pragma unroll
            for (int i = 0; i < 4; i++)
#pragma unroll
                for (int j = 0; j < 4; j++)
#pragma unroll
                    for (int r = 0; r < 4; r++) {
                        int row = tile_m + wm + i * 16 + quad * 4 + r;
                        int col = tile_n + wn + j * 16 + l16;
                        C[(long)row * ldc + col] = (OutT)(acc[i][j][r] * scale);
                    }
        }
    } else {
#pragma unroll
        for (int i = 0; i < 4; i++)
#pragma unroll
            for (int j = 0; j < 4; j++)
#pragma unroll
                for (int r = 0; r < 4; r++) {
                    int row = tile_m + wm + i * 16 + quad * 4 + r;
                    int col = tile_n + wn + j * 16 + l16;
                    C[(long)row * ldc + col] = (OutT)(acc[i][j][r] * scale);
                }
    }
}

// z<3: transpose+cast W_z fp32[in][out] -> Wt_z f16[out][in]; z==3: cast x->f16
__global__ void prep(const float* __restrict__ x,
                     const float* __restrict__ W0, const float* __restrict__ W1,
                     const float* __restrict__ W2,
                     f16* __restrict__ xb, f16* __restrict__ Wt) {
    if (blockIdx.z == 3) {
        long base = ((long)(blockIdx.y * 16 + blockIdx.x) * 256 + threadIdx.x) * 4;
#pragma unroll
        for (int it = 0; it < 16; it++) {
            long i = base + (long)it * (256 * 256 * 4);
            f32x4 v = *(const f32x4*)(x + i);
            f16x4 o;
            o.x = (f16)v.x; o.y = (f16)v.y; o.z = (f16)v.z; o.w = (f16)v.w;
            *(f16x4*)(xb + i) = o;
        }
        return;
    }
    __shared__ f16 tile[64][65];
    const float* W = blockIdx.z == 0 ? W0 : (blockIdx.z == 1 ? W1 : W2);
    f16* O = Wt + (long)blockIdx.z * DIN * DOUT;
    int r0 = blockIdx.y * 64;   // in-dim
    int c0 = blockIdx.x * 64;   // out-dim
    int tx = threadIdx.x & 63, ty = threadIdx.x >> 6;
#pragma unroll
    for (int i = 0; i < 16; i++)
        tile[ty + i * 4][tx] = (f16)W[(long)(r0 + ty + i * 4) * DOUT + c0 + tx];
    __syncthreads();
#pragma unroll
    for (int i = 0; i < 16; i++)
        O[(long)(c0 + ty + i * 4) * DIN + r0 + tx] = tile[tx][ty + i * 4];
}

// out = (p0+p1+p2+p3)/rowsum ; one block per output row; partials are f16.
__global__ __launch_bounds__(256)
void reduce_norm(const f16* __restrict__ p0, const f16* __restrict__ p1,
                 const f16* __restrict__ p2, const f16* __restrict__ p3,
                 const float* __restrict__ sums, float* __restrict__ out) {
    const int row = blockIdx.x;
    const int lane = threadIdx.x & 63;
    float s = sums[(long)row * 64 + lane];
#pragma unroll
    for (int msk = 1; msk < 64; msk <<= 1) s += __shfl_xor(s, msk, 64);
    const float inv = 1.f / s;
    long i = (long)row * 1024 + threadIdx.x * 4;
    f16x4 a = *(const f16x4*)(p0 + i);
    f16x4 b = *(const f16x4*)(p1 + i);
    f16x4 c = *(const f16x4*)(p2 + i);
    f16x4 d = *(const f16x4*)(p3 + i);
    f32x4 o;
    o.x = (((float)a.x + (float)b.x) + ((float)c.x + (float)d.x)) * inv;
    o.y = (((float)a.y + (float)b.y) + ((float)c.y + (float)d.y)) * inv;
    o.z = (((float)a.z + (float)b.z) + ((float)c.z + (float)d.z)) * inv;
    o.w = (((float)a.w + (float)b.w) + ((float)c.w + (float)d.w)) * inv;
    *(f32x4*)(out + i) = o;
}

extern "C" void kernel_launch(void* const* d_in, const int* in_sizes, int n_in,
                              void* d_out, int out_size, void* d_ws, size_t ws_size,
                              hipStream_t stream) {
    const float* x  = (const float*)d_in[0];
    const float* Wq = (const float*)d_in[1];
    const float* Wk = (const float*)d_in[2];
    const float* Wv = (const float*)d_in[3];
    float* out = (float*)d_out;
    char* ws = (char*)d_ws;
    const size_t MB = 1ull << 20;
    f16* xb  = (f16*)(ws);              // [0,8)   x f16; dead after QKV
    f16* Wt  = (f16*)(ws + 8 * MB);     // [8,14)  3x W^T f16
    f16* Qb  = (f16*)(ws + 14 * MB);    // [14,22) dead after S GEMM
    f16* Kb  = (f16*)(ws + 22 * MB);    // [22,30) dead after S GEMM
    f16* Vt  = (f16*)(ws + 30 * MB);    // [30,38) V^T f16 [dout][seq]
    f16* S   = (f16*)(ws + 38 * MB);    // [38,70) P' = exp(s/32), f16
    f16* scr0 = (f16*)(ws + 70 * MB);   // [70,78)  f16 PV partial 0
    f16* scr1 = (f16*)(ws + 78 * MB);   // [78,86)  f16 PV partial 1
    f16* scr2 = (f16*)(ws + 86 * MB);   // [86,94)  f16 PV partial 2
    f16* scr3 = (f16*)(ws + 94 * MB);   // [94,102) f16 PV partial 3
    float* Sums = (float*)(ws);         // 1 MB over dead xb (row partial sums)

    prep<<<dim3(16, 16, 4), 256, 0, stream>>>(x, Wq, Wk, Wv, xb, Wt);
    // z=0: Q, z=1: K, z=2: V written transposed to Vt  (proven 128^2 kernel)
    gemm_bt<f16, 1><<<dim3(8, 32, 3), 256, 0, stream>>>(
        xb, Wt, Qb, Kb, Qb, Qb, NSEQ, DOUT, DIN, DIN, DIN, DOUT, 1.0f,
        0, (long)DIN * DOUT, Vt, 2, NSEQ, nullptr);
    // P' = exp((Q @ K^T)/32) f16 + per-row partial sums  (256^2 8-phase)
    gemm8<f16, 2><<<dim3(16, 16, 1), 512, 0, stream>>>(
        Qb, Kb, S, S, S, S, NSEQ, NSEQ, DIN, DIN, DIN, NSEQ, 0.03125f,
        0, 0, Sums);
    // partial_z = P'[:, z*1024:(z+1)*1024] @ Vt[:, z*1024:(z+1)*1024]^T
    gemm8<f16, 0><<<dim3(4, 16, 4), 512, 0, stream>>>(
        S, Vt, scr0, scr1, scr2, scr3, NSEQ, DOUT, 1024, NSEQ, NSEQ, DOUT, 1.0f,
        1024, 1024, nullptr);
    reduce_norm<<<4096, 256, 0, stream>>>(scr0, scr1, scr2, scr3, Sums, out);
}

// Round 6
// 198.348 us; speedup vs baseline: 1.0218x; 1.0218x over previous
//
#include <hip/hip_runtime.h>
#include <math.h>

typedef _Float16 f16;
typedef __attribute__((ext_vector_type(8))) _Float16 f16x8;
typedef __attribute__((ext_vector_type(4))) _Float16 f16x4;
typedef __attribute__((ext_vector_type(4))) float f32x4;

#define NSEQ 4096
#define DIN 1024
#define DOUT 1024

// async global->LDS, 16B per lane; LDS dest must be wave-uniform base + lane*16
__device__ __forceinline__ void load16(const void* g, void* l) {
    __builtin_amdgcn_global_load_lds(
        (const __attribute__((address_space(1))) unsigned int*)g,
        (__attribute__((address_space(3))) unsigned int*)l, 16, 0, 0);
}

// R6: NO memory-clobber fences anywhere in the hot loop.  asm("... memory")
// forces SIInsertWaitcnts to drain vmcnt(0) before every barrier (it must
// assume the asm reads LDS that in-flight global_load_lds writes), which
// destroyed the counted-vmcnt pipeline in R1/R5 (8-phase ran exactly like
// the drain-per-step loop).  Ordering is instead built from:
//   - sched_barrier(0): compile-time pin (reads/stages stay in their phase)
//   - bare s_barrier:   runtime wave sync
//   - clobber-free "s_waitcnt vmcnt(N)": counted staging drain, once per tile
// ds_read->MFMA deps are compiler-visible VGPR deps: auto-waitcnt emits
// fine-grained lgkmcnt so early-landing operands start MFMA while the LDS
// pipe still services other waves (the pipe-overlap mechanism).
#define SB() __builtin_amdgcn_sched_barrier(0)
#define BARRIER() __builtin_amdgcn_s_barrier()

#define MM(I, J, KH, AR) \
    acc[I][J] = __builtin_amdgcn_mfma_f32_16x16x32_f16(AR[KH], b##J[KH], acc[I][J], 0, 0, 0)

// one phase's MFMA cluster: 2 m-frags x 4 n x 2 khalves = 16 MFMA, prio-wrapped (T5)
#define MFMA16(I0, I1) \
    __builtin_amdgcn_s_setprio(1); \
    MM(I0,0,0,a0); MM(I0,1,0,a0); MM(I0,2,0,a0); MM(I0,3,0,a0); \
    MM(I1,0,0,a1); MM(I1,1,0,a1); MM(I1,2,0,a1); MM(I1,3,0,a1); \
    MM(I0,0,1,a0); MM(I0,1,1,a0); MM(I0,2,1,a0); MM(I0,3,1,a0); \
    MM(I1,0,1,a1); MM(I1,1,1,a1); MM(I1,2,1,a1); MM(I1,3,1,a1); \
    __builtin_amdgcn_s_setprio(0)

// ---------------- 256x256 8-phase kernel (S and PV) ----------------
// C[M,N] = scale*(A[M,K] @ B[N,K]^T).  BK=64, 8 waves (2Mx4N), 128 KiB LDS
// double-buffered, 4 phases/K-tile x {ds_read subtile || 2 global_load_lds ->
// SB -> barrier -> setprio MFMA16 -> barrier}, counted vmcnt(4) once per tile.
// Layout per array: [buf(32768B)][kh(16384B)][row(64B)][32 f16].
// Staging is coalesced (16x 64B segments per load16): row-major LDS rows with
// intra-row chunk swizzle c(r)=(r+(r>>2))&3, global src permuted only within
// each row's 64B segment.  B(t+2) restages into buf[cur].B: WAR-safe because
// P1's b-reads are pinned above P1's barrier (SB) and 3 barriers precede the
// P3 stB issue.  vmcnt(4) at tile end: the 8 oldest loads (= A(t+1),B(t+1))
// have landed; B(t+2)'s 4 stay in flight across the barrier.
template <typename OutT, int EPI>
__global__ __launch_bounds__(512, 2)
void gemm8(const f16* __restrict__ A, const f16* __restrict__ B,
           OutT* __restrict__ c0, OutT* __restrict__ c1,
           OutT* __restrict__ c2, OutT* __restrict__ c3,
           int M, int N, int K, int lda, int ldb, int ldc, float scale,
           long aStrideZ, long bStrideZ, float* __restrict__ Sums)
{
    const int z = blockIdx.z;
    A += (long)z * aStrideZ;
    B += (long)z * bStrideZ;
    OutT* C = z == 0 ? c0 : (z == 1 ? c1 : (z == 2 ? c2 : c3));
    __shared__ f16 As[2 * 2 * 256 * 32];   // 64 KB: [buf][kh][row][32]
    __shared__ f16 Bs[2 * 2 * 256 * 32];   // 64 KB

    // ---- XCD swizzle: 8x4 patches when gx>=8; chunked otherwise ----
    const int gx = gridDim.x;
    const int bid = blockIdx.y * gx + blockIdx.x;
    int bx, by;
    if (gx >= 8) {
        int xcd = bid & 7, s = bid >> 3;
        int px = s & 7, rest = s >> 3;
        int py = rest & 3, chunk = rest >> 2;
        int pg = xcd + (chunk << 3);
        int pcols = gx >> 3;
        int lp = 31 - __clz(pcols);
        bx = ((pg & (pcols - 1)) << 3) + px;
        by = ((pg >> lp) << 2) + py;
    } else {
        int nwg = gx * gridDim.y;
        int nb = (bid & 7) * (nwg >> 3) + (bid >> 3);
        bx = nb % gx; by = nb / gx;
    }

    const int t    = threadIdx.x;
    const int lane = t & 63;
    const int w    = t >> 6;            // 0..7
    const int wm   = (w >> 2) * 128;    // 0,128
    const int wn   = (w & 3) * 64;      // 0..192
    const int tile_m = by * 256;
    const int tile_n = bx * 256;
    const int quad = lane >> 4;
    const int l16  = lane & 15;
    const int srow = t >> 2;
    const int scol = (((t & 3) + srow + (srow >> 2)) & 3) * 8;
    const int qx16 = ((quad - (l16 + (l16 >> 2))) & 3) * 16;

    f32x4 acc[8][4];
#pragma unroll
    for (int i = 0; i < 8; i++)
#pragma unroll
        for (int j = 0; j < 4; j++) acc[i][j] = (f32x4){0.f, 0.f, 0.f, 0.f};

    const f16* Ag = A + (long)(tile_m + srow) * lda + scol;
    const f16* Bg = B + (long)(tile_n + srow) * ldb + scol;
    const long a128 = (long)128 * lda, b128 = (long)128 * ldb;
    char* AsW = (char*)As + t * 16;
    char* BsW = (char*)Bs + t * 16;
    const char* aRd = (const char*)As + (wm + l16) * 64 + qx16;
    const char* bRd = (const char*)Bs + (wn + l16) * 64 + qx16;

    auto stA = [&](int buf, int kh, int rb, int k0) {
        load16(Ag + k0 + kh * 32 + (long)rb * a128,
               AsW + buf * 32768 + kh * 16384 + rb * 8192);
    };
    auto stB = [&](int buf, int kh, int rb, int k0) {
        load16(Bg + k0 + kh * 32 + (long)rb * b128,
               BsW + buf * 32768 + kh * 16384 + rb * 8192);
    };

    const int nt = K >> 6;
    // prologue: A(0),B(0)->buf0; B(1)->buf1 stays partially in flight
    stA(0,0,0,0); stA(0,0,1,0); stA(0,1,0,0); stA(0,1,1,0);
    stB(0,0,0,0); stB(0,0,1,0); stB(0,1,0,0); stB(0,1,1,0);
    if (nt > 1) {
        stB(1,0,0,64); stB(1,0,1,64); stB(1,1,0,64); stB(1,1,1,64);
        asm volatile("s_waitcnt vmcnt(4)");
    } else {
        asm volatile("s_waitcnt vmcnt(0)");
    }
    SB(); BARRIER(); SB();

    for (int ti = 0; ti < nt; ++ti) {
        const int cur = ti & 1;
        const char* aR = aRd + cur * 32768;
        const char* bR = bRd + cur * 32768;
        const int k1 = (ti + 1) << 6;
        const int k2 = (ti + 2) << 6;
        f16x8 b0[2], b1[2], b2[2], b3[2], a0[2], a1[2];
        // ---- P1: all B + A m0,m1 (kh0 first for early MFMA start); stage A(t+1) kh0 ----
        b0[0] = *(const f16x8*)(bR);          b1[0] = *(const f16x8*)(bR + 1024);
        b2[0] = *(const f16x8*)(bR + 2048);   b3[0] = *(const f16x8*)(bR + 3072);
        a0[0] = *(const f16x8*)(aR);          a1[0] = *(const f16x8*)(aR + 1024);
        b0[1] = *(const f16x8*)(bR + 16384);  b1[1] = *(const f16x8*)(bR + 17408);
        b2[1] = *(const f16x8*)(bR + 18432);  b3[1] = *(const f16x8*)(bR + 19456);
        a0[1] = *(const f16x8*)(aR + 16384);  a1[1] = *(const f16x8*)(aR + 17408);
        if (ti + 1 < nt) { stA(cur ^ 1, 0, 0, k1); stA(cur ^ 1, 0, 1, k1); }
        SB(); BARRIER();
        MFMA16(0, 1);
        BARRIER();
        // ---- P2: A m2,m3; stage A(t+1) kh1 ----
        a0[0] = *(const f16x8*)(aR + 2048);   a1[0] = *(const f16x8*)(aR + 3072);
        a0[1] = *(const f16x8*)(aR + 18432);  a1[1] = *(const f16x8*)(aR + 19456);
        if (ti + 1 < nt) { stA(cur ^ 1, 1, 0, k1); stA(cur ^ 1, 1, 1, k1); }
        SB(); BARRIER();
        MFMA16(2, 3);
        BARRIER();
        // ---- P3: A m4,m5; stage B(t+2) kh0 into buf[cur] (B consumed in P1) ----
        a0[0] = *(const f16x8*)(aR + 4096);   a1[0] = *(const f16x8*)(aR + 5120);
        a0[1] = *(const f16x8*)(aR + 20480);  a1[1] = *(const f16x8*)(aR + 21504);
        if (ti + 2 < nt) { stB(cur, 0, 0, k2); stB(cur, 0, 1, k2); }
        SB(); BARRIER();
        MFMA16(4, 5);
        BARRIER();
        // ---- P4: A m6,m7; stage B(t+2) kh1; counted drain, once per tile ----
        a0[0] = *(const f16x8*)(aR + 6144);   a1[0] = *(const f16x8*)(aR + 7168);
        a0[1] = *(const f16x8*)(aR + 22528);  a1[1] = *(const f16x8*)(aR + 23552);
        if (ti + 2 < nt) { stB(cur, 1, 0, k2); stB(cur, 1, 1, k2); }
        SB(); BARRIER();
        MFMA16(6, 7);
        if (ti + 2 < nt)      asm volatile("s_waitcnt vmcnt(4)");
        else if (ti + 1 < nt) asm volatile("s_waitcnt vmcnt(0)");
        SB(); BARRIER(); SB();   // next-tile reads pinned below the drain
    }

    // epilogue: D row = quad*4 + reg, col = lane&15 (verified m89/m91 layout)
    if (EPI == 2) {
        const int bxs = bx * 4 + (wn >> 6);   // 16 bx * 4 wave-cols = 64 chunks
#pragma unroll
        for (int i = 0; i < 8; i++) {
            float rs[4] = {0.f, 0.f, 0.f, 0.f};
#pragma unroll
            for (int j = 0; j < 4; j++)
#pragma unroll
                for (int r = 0; r < 4; r++) {
                    float e = __expf(acc[i][j][r] * scale);
                    int row = tile_m + wm + i * 16 + quad * 4 + r;
                    int col = tile_n + wn + j * 16 + l16;
                    C[(long)row * ldc + col] = (OutT)e;
                    rs[r] += e;
                }
#pragma unroll
            for (int msk = 1; msk < 16; msk <<= 1)
#pragma unroll
                for (int r = 0; r < 4; r++)
                    rs[r] += __shfl_xor(rs[r], msk, 64);
            if (l16 == 0)
#pragma unroll
                for (int r = 0; r < 4; r++) {
                    int row = tile_m + wm + i * 16 + quad * 4 + r;
                    Sums[(long)row * 64 + bxs] = rs[r];
                }
        }
    } else {
#pragma unroll
        for (int i = 0; i < 8; i++)
#pragma unroll
            for (int j = 0; j < 4; j++)
#pragma unroll
                for (int r = 0; r < 4; r++) {
                    int row = tile_m + wm + i * 16 + quad * 4 + r;
                    int col = tile_n + wn + j * 16 + l16;
                    C[(long)row * ldc + col] = (OutT)(acc[i][j][r] * scale);
                }
    }
}

// ---------------- 128x128 proven kernel (QKV) ----------------
template <typename OutT, int EPI>
__global__ __launch_bounds__(256, 2)
void gemm_bt(const f16* __restrict__ A, const f16* __restrict__ B,
             OutT* __restrict__ c0, OutT* __restrict__ c1,
             OutT* __restrict__ c2, OutT* __restrict__ c3,
             int M, int N, int K, int lda, int ldb, int ldc, float scale,
             long aStrideZ, long bStrideZ,
             f16* __restrict__ TC, int tz, int ldt, float* __restrict__ Sums)
{
    const int z = blockIdx.z;
    A += (long)z * aStrideZ;
    B += (long)z * bStrideZ;
    OutT* C = z == 0 ? c0 : (z == 1 ? c1 : (z == 2 ? c2 : c3));
    __shared__ f16 As[2 * 128 * 32];
    __shared__ f16 Bs[2 * 128 * 32];

    int gx = gridDim.x;
    int bid = blockIdx.y * gx + blockIdx.x;
    int xcd = bid & 7, s = bid >> 3;
    int px = s & 7, rest = s >> 3;
    int py = rest & 3, chunk = rest >> 2;
    int pg = xcd + (chunk << 3);
    int pcols = gx >> 3;
    int lp = 31 - __clz(pcols);
    int bx = ((pg & (pcols - 1)) << 3) + px;
    int by = ((pg >> lp) << 2) + py;

    const int t    = threadIdx.x;
    const int lane = t & 63;
    const int wave = t >> 6;
    const int wm   = (wave >> 1) * 64;
    const int wn   = (wave & 1) * 64;
    const int tile_m = by * 128;
    const int tile_n = bx * 128;
    const int quad = lane >> 4;
    const int l16  = lane & 15;
    const int srow = t >> 2;
    const int scol = (((t & 3) + srow + (srow >> 2)) & 3) * 8;
    const int qx8 = ((quad - (l16 + (l16 >> 2))) & 3) * 8;

    f32x4 acc[4][4];
#pragma unroll
    for (int i = 0; i < 4; i++)
#pragma unroll
        for (int j = 0; j < 4; j++)
            acc[i][j] = (f32x4){0.f, 0.f, 0.f, 0.f};

    const f16* Ab = A + (long)(tile_m + srow) * lda + scol;
    const f16* Bb = B + (long)(tile_n + srow) * ldb + scol;
    f16* Asd = As + t * 8;
    f16* Bsd = Bs + t * 8;

    for (int k0 = 0; k0 < K; k0 += 64) {
        load16(Ab + k0, Asd);
        load16(Ab + (long)64 * lda + k0, Asd + 2048);
        load16(Ab + k0 + 32, Asd + 4096);
        load16(Ab + (long)64 * lda + k0 + 32, Asd + 4096 + 2048);
        load16(Bb + k0, Bsd);
        load16(Bb + (long)64 * ldb + k0, Bsd + 2048);
        load16(Bb + k0 + 32, Bsd + 4096);
        load16(Bb + (long)64 * ldb + k0 + 32, Bsd + 4096 + 2048);
        __syncthreads();
#pragma unroll
        for (int p = 0; p < 2; p++) {
            f16x8 a[4], b[4];
#pragma unroll
            for (int i = 0; i < 4; i++)
                a[i] = *(const f16x8*)(As + p * 4096 + (wm + i * 16 + l16) * 32 + qx8);
#pragma unroll
            for (int j = 0; j < 4; j++)
                b[j] = *(const f16x8*)(Bs + p * 4096 + (wn + j * 16 + l16) * 32 + qx8);
#pragma unroll
            for (int i = 0; i < 4; i++)
#pragma unroll
                for (int j = 0; j < 4; j++)
                    acc[i][j] = __builtin_amdgcn_mfma_f32_16x16x32_f16(
                        a[i], b[j], acc[i][j], 0, 0, 0);
        }
        __syncthreads();
    }
    if (EPI == 1) {
        if (z == tz) {
#pragma unroll
            for (int i = 0; i < 4; i++)
#pragma unroll
                for (int j = 0; j < 4; j++) {
                    f16x4 o;
#pragma unroll
                    for (int r = 0; r < 4; r++) o[r] = (f16)(acc[i][j][r] * scale);
                    int row0 = tile_m + wm + i * 16 + quad * 4;
                    int col  = tile_n + wn + j * 16 + l16;
                    *(f16x4*)(TC + (long)col * ldt + row0) = o;
                }
        } else {
#pragma unroll
            for (int i = 0; i < 4; i++)
#pragma unroll
                for (int j = 0; j < 4; j++)
#pragma unroll
                    for (int r = 0; r < 4; r++) {
                        int row = tile_m + wm + i * 16 + quad * 4 + r;
                        int col = tile_n + wn + j * 16 + l16;
                        C[(long)row * ldc + col] = (OutT)(acc[i][j][r] * scale);
                    }
        }
    } else {
#pragma unroll
        for (int i = 0; i < 4; i++)
#pragma unroll
            for (int j = 0; j < 4; j++)
#pragma unroll
                for (int r = 0; r < 4; r++) {
                    int row = tile_m + wm + i * 16 + quad * 4 + r;
                    int col = tile_n + wn + j * 16 + l16;
                    C[(long)row * ldc + col] = (OutT)(acc[i][j][r] * scale);
                }
    }
}

// z<3: transpose+cast W_z fp32[in][out] -> Wt_z f16[out][in]; z==3: cast x->f16
__global__ void prep(const float* __restrict__ x,
                     const float* __restrict__ W0, const float* __restrict__ W1,
                     const float* __restrict__ W2,
                     f16* __restrict__ xb, f16* __restrict__ Wt) {
    if (blockIdx.z == 3) {
        long base = ((long)(blockIdx.y * 16 + blockIdx.x) * 256 + threadIdx.x) * 4;
#pragma unroll
        for (int it = 0; it < 16; it++) {
            long i = base + (long)it * (256 * 256 * 4);
            f32x4 v = *(const f32x4*)(x + i);
            f16x4 o;
            o.x = (f16)v.x; o.y = (f16)v.y; o.z = (f16)v.z; o.w = (f16)v.w;
            *(f16x4*)(xb + i) = o;
        }
        return;
    }
    __shared__ f16 tile[64][65];
    const float* W = blockIdx.z == 0 ? W0 : (blockIdx.z == 1 ? W1 : W2);
    f16* O = Wt + (long)blockIdx.z * DIN * DOUT;
    int r0 = blockIdx.y * 64;   // in-dim
    int c0 = blockIdx.x * 64;   // out-dim
    int tx = threadIdx.x & 63, ty = threadIdx.x >> 6;
#pragma unroll
    for (int i = 0; i < 16; i++)
        tile[ty + i * 4][tx] = (f16)W[(long)(r0 + ty + i * 4) * DOUT + c0 + tx];
    __syncthreads();
#pragma unroll
    for (int i = 0; i < 16; i++)
        O[(long)(c0 + ty + i * 4) * DIN + r0 + tx] = tile[tx][ty + i * 4];
}

// out = (p0+p1+p2+p3)/rowsum ; one block per output row; partials are f16.
__global__ __launch_bounds__(256)
void reduce_norm(const f16* __restrict__ p0, const f16* __restrict__ p1,
                 const f16* __restrict__ p2, const f16* __restrict__ p3,
                 const float* __restrict__ sums, float* __restrict__ out) {
    const int row = blockIdx.x;
    const int lane = threadIdx.x & 63;
    float s = sums[(long)row * 64 + lane];
#pragma unroll
    for (int msk = 1; msk < 64; msk <<= 1) s += __shfl_xor(s, msk, 64);
    const float inv = 1.f / s;
    long i = (long)row * 1024 + threadIdx.x * 4;
    f16x4 a = *(const f16x4*)(p0 + i);
    f16x4 b = *(const f16x4*)(p1 + i);
    f16x4 c = *(const f16x4*)(p2 + i);
    f16x4 d = *(const f16x4*)(p3 + i);
    f32x4 o;
    o.x = (((float)a.x + (float)b.x) + ((float)c.x + (float)d.x)) * inv;
    o.y = (((float)a.y + (float)b.y) + ((float)c.y + (float)d.y)) * inv;
    o.z = (((float)a.z + (float)b.z) + ((float)c.z + (float)d.z)) * inv;
    o.w = (((float)a.w + (float)b.w) + ((float)c.w + (float)d.w)) * inv;
    *(f32x4*)(out + i) = o;
}

extern "C" void kernel_launch(void* const* d_in, const int* in_sizes, int n_in,
                              void* d_out, int out_size, void* d_ws, size_t ws_size,
                              hipStream_t stream) {
    const float* x  = (const float*)d_in[0];
    const float* Wq = (const float*)d_in[1];
    const float* Wk = (const float*)d_in[2];
    const float* Wv = (const float*)d_in[3];
    float* out = (float*)d_out;
    char* ws = (char*)d_ws;
    const size_t MB = 1ull << 20;
    f16* xb  = (f16*)(ws);              // [0,8)   x f16; dead after QKV
    f16* Wt  = (f16*)(ws + 8 * MB);     // [8,14)  3x W^T f16
    f16* Qb  = (f16*)(ws + 14 * MB);    // [14,22) dead after S GEMM
    f16* Kb  = (f16*)(ws + 22 * MB);    // [22,30) dead after S GEMM
    f16* Vt  = (f16*)(ws + 30 * MB);    // [30,38) V^T f16 [dout][seq]
    f16* S   = (f16*)(ws + 38 * MB);    // [38,70) P' = exp(s/32), f16
    f16* scr0 = (f16*)(ws + 70 * MB);   // [70,78)  f16 PV partial 0
    f16* scr1 = (f16*)(ws + 78 * MB);   // [78,86)  f16 PV partial 1
    f16* scr2 = (f16*)(ws + 86 * MB);   // [86,94)  f16 PV partial 2
    f16* scr3 = (f16*)(ws + 94 * MB);   // [94,102) f16 PV partial 3
    float* Sums = (float*)(ws);         // 1 MB over dead xb (row partial sums)

    prep<<<dim3(16, 16, 4), 256, 0, stream>>>(x, Wq, Wk, Wv, xb, Wt);
    // z=0: Q, z=1: K, z=2: V written transposed to Vt  (proven 128^2 kernel)
    gemm_bt<f16, 1><<<dim3(8, 32, 3), 256, 0, stream>>>(
        xb, Wt, Qb, Kb, Qb, Qb, NSEQ, DOUT, DIN, DIN, DIN, DOUT, 1.0f,
        0, (long)DIN * DOUT, Vt, 2, NSEQ, nullptr);
    // P' = exp((Q @ K^T)/32) f16 + per-row partial sums  (256^2 8-phase)
    gemm8<f16, 2><<<dim3(16, 16, 1), 512, 0, stream>>>(
        Qb, Kb, S, S, S, S, NSEQ, NSEQ, DIN, DIN, DIN, NSEQ, 0.03125f,
        0, 0, Sums);
    // partial_z = P'[:, z*1024:(z+1)*1024] @ Vt[:, z*1024:(z+1)*1024]^T
    gemm8<f16, 0><<<dim3(4, 16, 4), 512, 0, stream>>>(
        S, Vt, scr0, scr1, scr2, scr3, NSEQ, DOUT, 1024, NSEQ, NSEQ, DOUT, 1.0f,
        1024, 1024, nullptr);
    reduce_norm<<<4096, 256, 0, stream>>>(scr0, scr1, scr2, scr3, Sums, out);
}